// Round 4
// baseline (75.514 us; speedup 1.0000x reference)
//
#include <hip/hip_runtime.h>

#define BB 1024
#define QQ 128
#define TT 32
#define NC 257
#define FINF 1e9f
#define LDA (QQ + 2)   // LDS row stride: 130 -> 2-way bank aliasing (free)

// ---------- fast cross-lane helpers (DPP + readlane; no ds_swizzle) ----------
__device__ __forceinline__ int rl_i(int v, int l) {
    return __builtin_amdgcn_readlane(v, l);
}
__device__ __forceinline__ float rl_f(float v, int l) {
    return __int_as_float(__builtin_amdgcn_readlane(__float_as_int(v), l));
}
#define DPP_STEP_MIN(x, ctrl) \
    x = fminf(x, __int_as_float(__builtin_amdgcn_update_dpp( \
        __float_as_int(x), __float_as_int(x), ctrl, 0xf, 0xf, false)))
#define DPP_STEP_MAX(x, ctrl) \
    x = fmaxf(x, __int_as_float(__builtin_amdgcn_update_dpp( \
        __float_as_int(x), __float_as_int(x), ctrl, 0xf, 0xf, false)))
#define DPP_STEP_ADD(x, ctrl) \
    x = x + __int_as_float(__builtin_amdgcn_update_dpp( \
        0, __float_as_int(x), ctrl, 0xf, 0xf, false))

__device__ __forceinline__ float wave_min64(float x) {
    DPP_STEP_MIN(x, 0xB1); DPP_STEP_MIN(x, 0x4E);
    DPP_STEP_MIN(x, 0x141); DPP_STEP_MIN(x, 0x140);
    DPP_STEP_MIN(x, 0x142); DPP_STEP_MIN(x, 0x143);
    return rl_f(x, 63);
}
__device__ __forceinline__ float wave_max64(float x) {
    DPP_STEP_MAX(x, 0xB1); DPP_STEP_MAX(x, 0x4E);
    DPP_STEP_MAX(x, 0x141); DPP_STEP_MAX(x, 0x140);
    DPP_STEP_MAX(x, 0x142); DPP_STEP_MAX(x, 0x143);
    return rl_f(x, 63);
}
__device__ __forceinline__ float wave_add64(float x) {
    DPP_STEP_ADD(x, 0xB1); DPP_STEP_ADD(x, 0x4E);
    DPP_STEP_ADD(x, 0x141); DPP_STEP_ADD(x, 0x140);
    DPP_STEP_ADD(x, 0x142); DPP_STEP_ADD(x, 0x143);
    return rl_f(x, 63);
}

// ---------------- Fused kernel: cost matrix + JV LSA, one block per batch ----
__global__ __launch_bounds__(256) void fused_kernel(
    const float* __restrict__ logits,
    const float4* __restrict__ pboxes,
    const int* __restrict__ tlabels,
    const float4* __restrict__ tboxes,
    float* __restrict__ Cmat,
    float* __restrict__ rows_out,
    float* __restrict__ cols_out)
{
    const int b = blockIdx.x;
    const int tid = threadIdx.x;
    const int wave = tid >> 6;
    const int lane = tid & 63;

    __shared__ float a[TT][LDA];     // cost tile, transposed: a[t][q]
    __shared__ float4 tb_s[TT];
    __shared__ int lbl_s[TT];
    __shared__ float umin_s[TT];
    __shared__ int x4row[TT];

    if (tid < TT) {
        tb_s[tid] = tboxes[b * TT + tid];
        lbl_s[tid] = tlabels[b * TT + tid];
    }
    // each wave owns rows q0..q0+31; preload its pred boxes (1/lane, bcast later)
    const int q0 = wave * 32;
    const float4 pbv = pboxes[b * QQ + q0 + (lane & 31)];
    __syncthreads();

    // ---- phase 1: softmax + cost rows -> LDS ----
    #pragma unroll 2
    for (int qi = 0; qi < 32; ++qi) {
        const int q = q0 + qi;
        const float* lrow = logits + ((size_t)b * QQ + q) * NC;
        const float4 x = reinterpret_cast<const float4*>(lrow)[lane];
        float mloc = fmaxf(fmaxf(x.x, x.y), fmaxf(x.z, x.w));
        float xt = 0.f;
        if (lane == 0) { xt = lrow[256]; mloc = fmaxf(mloc, xt); }
        const float m = wave_max64(mloc);
        float sloc = expf(x.x - m) + expf(x.y - m) + expf(x.z - m) + expf(x.w - m);
        if (lane == 0) sloc += expf(xt - m);
        const float s = wave_add64(sloc);

        const float pbx = rl_f(pbv.x, qi), pby = rl_f(pbv.y, qi);
        const float pbz = rl_f(pbv.z, qi), pbw = rl_f(pbv.w, qi);
        const float px0 = pbx - 0.5f * pbz, py0 = pby - 0.5f * pbw;
        const float px1 = pbx + 0.5f * pbz, py1 = pby + 0.5f * pbw;
        const float parea = (px1 - px0) * (py1 - py0);

        if (lane < TT) {
            const int t = lane;
            const float cls = -(expf(lrow[lbl_s[t]] - m) / s);
            const float4 tb = tb_s[t];
            const float cb = fabsf(pbx - tb.x) + fabsf(pby - tb.y)
                           + fabsf(pbz - tb.z) + fabsf(pbw - tb.w);
            const float tx0 = tb.x - 0.5f * tb.z, ty0 = tb.y - 0.5f * tb.w;
            const float tx1 = tb.x + 0.5f * tb.z, ty1 = tb.y + 0.5f * tb.w;
            const float tarea = (tx1 - tx0) * (ty1 - ty0);
            const float iw = fmaxf(fminf(px1, tx1) - fmaxf(px0, tx0), 0.f);
            const float ih = fmaxf(fminf(py1, ty1) - fmaxf(py0, ty0), 0.f);
            const float inter = iw * ih;
            const float uni = parea + tarea - inter;
            const float iou = inter / uni;
            const float cw = fmaxf(fmaxf(px1, tx1) - fminf(px0, tx0), 0.f);
            const float ch = fmaxf(fmaxf(py1, ty1) - fminf(py0, ty0), 0.f);
            const float ca = cw * ch;
            const float giou = iou - (ca - uni) / (ca + 1e-6f);
            a[t][q] = 5.0f * cb + cls - 2.0f * giou;
        }
    }
    __syncthreads();

    // ---- phase 1.25: C tile LDS -> global, dwordx4 coalesced ----
    {
        float4* Cb4 = reinterpret_cast<float4*>(Cmat + (size_t)b * QQ * TT);
        #pragma unroll
        for (int it = 0; it < 4; ++it) {
            const int idx = it * 256 + tid;   // float4 slot = idx (q*32+t)/4
            const int q = idx >> 3;
            const int t04 = (idx & 7) * 4;
            Cb4[idx] = make_float4(a[t04][q], a[t04 + 1][q],
                                   a[t04 + 2][q], a[t04 + 3][q]);
        }
    }

    // ---- phase 1.5: row mins, wave-parallel (wave w: rows 8w..8w+7) ----
    #pragma unroll
    for (int k = 0; k < 8; ++k) {
        const int t = wave * 8 + k;
        const float2 ar = *(const float2*)&a[t][2 * lane];
        const float mn = wave_min64(fminf(ar.x, ar.y));
        if (lane == 0) umin_s[t] = mn;
    }
    __syncthreads();

    // ---- phase 2: wave 0 runs JV LSA ----
    if (wave == 0) {
        float v0 = 0.f, v1 = 0.f;
        int p0 = -1, p1 = -1;             // row assigned to col 2l / 2l+1
        float u = (lane < TT) ? umin_s[lane] : 0.f;   // row duals (lanes<32)
        const float um_l = u;
        bool rowfree = (lane < TT);

        // greedy tight-edge assignment (u=rowmin, v=0 feasible)
        #pragma unroll
        for (int i = 0; i < TT; ++i) {
            const float2 ar = *(const float2*)&a[i][2 * lane];
            const float um = rl_f(um_l, i);
            const bool cand0 = (ar.x == um) & (p0 < 0);
            const bool cand1 = (ar.y == um) & (p1 < 0);
            const unsigned long long m0 = __ballot(cand0);
            const unsigned long long mm = m0 | __ballot(cand1);
            if (mm) {
                const int sl = __ffsll(mm) - 1;
                const bool pick0 = (m0 >> sl) & 1;
                if (lane == sl) { if (pick0) p0 = i; else p1 = i; }
                if (lane == i) rowfree = false;
            }
        }

        // Dijkstra augmentation for remaining free rows
        unsigned long long freerows = __ballot(rowfree);
        while (freerows) {
            const int i = __ffsll(freerows) - 1;
            freerows &= freerows - 1;

            float minv0 = FINF, minv1 = FINF;
            int way0 = -1, way1 = -1;
            bool used0 = false, used1 = false;
            bool in_tree = (lane == i);
            int i0 = i;
            int jcur = -1;
            int jfree;

            while (true) {
                const float ui0 = rl_f(u, i0);
                const float2 ar = *(const float2*)&a[i0][2 * lane];
                const float c0 = ar.x - ui0 - v0;
                const float c1 = ar.y - ui0 - v1;
                if (!used0 && c0 < minv0) { minv0 = c0; way0 = jcur; }
                if (!used1 && c1 < minv1) { minv1 = c1; way1 = jcur; }
                const float m0 = used0 ? FINF : minv0;
                const float m1 = used1 ? FINF : minv1;
                const float lv = fminf(m0, m1);
                const float delta = wave_min64(lv);
                const unsigned long long eq = __ballot(lv == delta);
                const int sl = __ffsll(eq) - 1;
                const unsigned long long which0 = __ballot(m0 <= m1);
                const int j1 = 2 * sl + (((which0 >> sl) & 1) ? 0 : 1);
                // dual updates
                if (used0) v0 -= delta; else minv0 -= delta;
                if (used1) v1 -= delta; else minv1 -= delta;
                if (in_tree) u += delta;
                // examine column j1
                const int pj1 = rl_i((j1 & 1) ? p1 : p0, j1 >> 1);
                if (pj1 < 0) { jfree = j1; break; }
                if (lane == (j1 >> 1)) { if (j1 & 1) used1 = true; else used0 = true; }
                if (lane == pj1) in_tree = true;
                i0 = pj1;
                jcur = j1;
            }

            // augment back to the root
            int j = jfree;
            while (true) {
                const int jprev = rl_i((j & 1) ? way1 : way0, j >> 1);
                const int pnew = (jprev < 0) ? i
                               : rl_i((jprev & 1) ? p1 : p0, jprev >> 1);
                if (lane == (j >> 1)) { if (j & 1) p1 = pnew; else p0 = pnew; }
                if (jprev < 0) break;
                j = jprev;
            }
        }

        // scatter col->row into row->col map
        if (p0 >= 0) x4row[p0] = 2 * lane;
        if (p1 >= 0) x4row[p1] = 2 * lane + 1;
    }
    __syncthreads();

    // ---- output: rank-sort by assigned q ascending ----
    if (wave == 0 && lane < TT) {
        const int val = x4row[lane];      // q assigned to target 'lane'
        int rank = 0;
        #pragma unroll
        for (int t2 = 0; t2 < TT; ++t2) {
            const int other = rl_i(val, t2);
            rank += (other < val) ? 1 : 0;
        }
        rows_out[b * TT + rank] = (float)val;
        cols_out[b * TT + rank] = (float)lane;
    }
}

extern "C" void kernel_launch(void* const* d_in, const int* in_sizes, int n_in,
                              void* d_out, int out_size, void* d_ws, size_t ws_size,
                              hipStream_t stream)
{
    const float*  logits  = (const float*)d_in[0];
    const float4* pboxes  = (const float4*)d_in[1];
    const int*    tlabels = (const int*)d_in[2];
    const float4* tboxes  = (const float4*)d_in[3];
    float* out  = (float*)d_out;
    float* Cmat = out;                                   // [B,Q,T] float
    float* rows = out + (size_t)BB * QQ * TT;            // [B,T] as float
    float* cols = rows + (size_t)BB * TT;                // [B,T] as float
    fused_kernel<<<BB, 256, 0, stream>>>(logits, pboxes, tlabels, tboxes,
                                         Cmat, rows, cols);
}